// Round 1
// baseline (1111.834 us; speedup 1.0000x reference)
//
#include <hip/hip_runtime.h>
#include <hip/hip_bf16.h>
#include <cstddef>

#define N_NODES 100000
#define E_EDGES 1600000
#define TOT_EDGES (E_EDGES + N_NODES)
#define NEG_SLOPE 0.2f
#define BN_EPS 1e-5f

// ---------------------------------------------------------------------------
// CSR build: histogram of dst, exclusive scan, scatter src ids by dst.
// ---------------------------------------------------------------------------

__global__ __launch_bounds__(256) void count_kernel(const int* __restrict__ ei,
                                                    int* __restrict__ counts) {
    int idx = blockIdx.x * blockDim.x + threadIdx.x;
    int stride = gridDim.x * blockDim.x;
    for (int e = idx; e < TOT_EDGES; e += stride) {
        int d = (e < E_EDGES) ? ei[E_EDGES + e] : (e - E_EDGES);
        atomicAdd(&counts[d], 1);
    }
}

// per-256-chunk sums
__global__ __launch_bounds__(256) void scan_partial(const int* __restrict__ counts,
                                                    int* __restrict__ partials) {
    __shared__ int s[256];
    int t = threadIdx.x;
    int i = blockIdx.x * 256 + t;
    s[t] = (i < N_NODES) ? counts[i] : 0;
    __syncthreads();
    for (int off = 128; off; off >>= 1) {
        if (t < off) s[t] += s[t + off];
        __syncthreads();
    }
    if (t == 0) partials[blockIdx.x] = s[0];
}

// exclusive scan of up to 512 partials in one block
__global__ __launch_bounds__(512) void scan_partials_kernel(int* __restrict__ partials, int nb) {
    __shared__ int s[512];
    int t = threadIdx.x;
    int v = (t < nb) ? partials[t] : 0;
    s[t] = v;
    __syncthreads();
    for (int off = 1; off < 512; off <<= 1) {
        int y = (t >= off) ? s[t - off] : 0;
        __syncthreads();
        s[t] += y;
        __syncthreads();
    }
    if (t < nb) partials[t] = s[t] - v;  // exclusive
}

__global__ __launch_bounds__(256) void scan_final(const int* __restrict__ counts,
                                                  const int* __restrict__ partials,
                                                  int* __restrict__ row_ptr,
                                                  int* __restrict__ write_pos) {
    __shared__ int s[256];
    int t = threadIdx.x;
    int i = blockIdx.x * 256 + t;
    int v = (i < N_NODES) ? counts[i] : 0;
    s[t] = v;
    __syncthreads();
    for (int off = 1; off < 256; off <<= 1) {
        int y = (t >= off) ? s[t - off] : 0;
        __syncthreads();
        s[t] += y;
        __syncthreads();
    }
    int excl = s[t] - v;  // exclusive within block
    int rp = partials[blockIdx.x] + excl;
    if (i <= N_NODES) row_ptr[i] = rp;
    if (i < N_NODES) write_pos[i] = rp;
}

__global__ __launch_bounds__(256) void scatter_kernel(const int* __restrict__ ei,
                                                      int* __restrict__ write_pos,
                                                      int* __restrict__ src_sorted) {
    int idx = blockIdx.x * blockDim.x + threadIdx.x;
    int stride = gridDim.x * blockDim.x;
    for (int e = idx; e < TOT_EDGES; e += stride) {
        int srcv, d;
        if (e < E_EDGES) { srcv = ei[e]; d = ei[E_EDGES + e]; }
        else             { srcv = e - E_EDGES; d = srcv; }
        int p = atomicAdd(&write_pos[d], 1);
        src_sorted[p] = srcv;
    }
}

// ---------------------------------------------------------------------------
// fp32 tiled GEMM: C[M,Nn] = A[M,K] @ B[K,Nn].  K % 16 == 0, Nn % 4 == 0.
// ---------------------------------------------------------------------------
#define TM 64
#define TN 64
#define TKK 16

__global__ __launch_bounds__(256) void gemm_kernel(const float* __restrict__ A,
                                                   const float* __restrict__ B,
                                                   float* __restrict__ C,
                                                   int M, int K, int Nn) {
    __shared__ float As[TKK][TM + 4];
    __shared__ float Bs[TKK][TN + 4];
    int t = threadIdx.x;
    int m0 = blockIdx.y * TM;
    int n0 = blockIdx.x * TN;
    int ty = t / 16, tx = t % 16;

    int am = t / 4;            // A row within tile (0..63)
    int ak = (t % 4) * 4;      // A k within tile (0,4,8,12)
    int bk = t / 16;           // B k within tile (0..15)
    int bn = (t * 4) % TN;     // B col within tile

    float acc[4][4] = {};

    for (int k0 = 0; k0 < K; k0 += TKK) {
        // load A tile (transposed into LDS)
        {
            int gm = m0 + am;
            float4 v = make_float4(0.f, 0.f, 0.f, 0.f);
            if (gm < M)
                v = *reinterpret_cast<const float4*>(A + (size_t)gm * K + k0 + ak);
            As[ak + 0][am] = v.x;
            As[ak + 1][am] = v.y;
            As[ak + 2][am] = v.z;
            As[ak + 3][am] = v.w;
        }
        // load B tile
        {
            int gk = k0 + bk;
            int gn = n0 + bn;
            float4 v = make_float4(0.f, 0.f, 0.f, 0.f);
            if (gn + 3 < Nn) {
                v = *reinterpret_cast<const float4*>(B + (size_t)gk * Nn + gn);
            } else {
                float tmp[4] = {0.f, 0.f, 0.f, 0.f};
                for (int j = 0; j < 4; j++)
                    if (gn + j < Nn) tmp[j] = B[(size_t)gk * Nn + gn + j];
                v = make_float4(tmp[0], tmp[1], tmp[2], tmp[3]);
            }
            *reinterpret_cast<float4*>(&Bs[bk][bn]) = v;
        }
        __syncthreads();
#pragma unroll
        for (int k = 0; k < TKK; k++) {
            float a[4], b[4];
#pragma unroll
            for (int i = 0; i < 4; i++) a[i] = As[k][ty * 4 + i];
#pragma unroll
            for (int j = 0; j < 4; j++) b[j] = Bs[k][tx * 4 + j];
#pragma unroll
            for (int i = 0; i < 4; i++)
#pragma unroll
                for (int j = 0; j < 4; j++) acc[i][j] += a[i] * b[j];
        }
        __syncthreads();
    }

#pragma unroll
    for (int i = 0; i < 4; i++) {
        int gm = m0 + ty * 4 + i;
        if (gm >= M) continue;
        int gn = n0 + tx * 4;
        if (gn + 3 < Nn) {
            float4 v = make_float4(acc[i][0], acc[i][1], acc[i][2], acc[i][3]);
            *reinterpret_cast<float4*>(C + (size_t)gm * Nn + gn) = v;
        } else {
            for (int j = 0; j < 4; j++)
                if (gn + j < Nn) C[(size_t)gm * Nn + gn + j] = acc[i][j];
        }
    }
}

// ---------------------------------------------------------------------------
// alpha_src[n] = h[n,:] . a_s ; alpha_dst[n] = h[n,:] . a_d   (wave per node)
// ---------------------------------------------------------------------------
template <int F>
__global__ __launch_bounds__(256) void row_dots(const float* __restrict__ h,
                                                const float* __restrict__ a_s,
                                                const float* __restrict__ a_d,
                                                float* __restrict__ asrc,
                                                float* __restrict__ adst) {
    int wave = threadIdx.x >> 6;
    int lane = threadIdx.x & 63;
    int node = blockIdx.x * 4 + wave;
    if (node >= N_NODES) return;
    float ps = 0.f, pd = 0.f;
    for (int f = lane; f < F; f += 64) {
        float v = h[(size_t)node * F + f];
        ps += v * a_s[f];
        pd += v * a_d[f];
    }
#pragma unroll
    for (int off = 32; off; off >>= 1) {
        ps += __shfl_xor(ps, off);
        pd += __shfl_xor(pd, off);
    }
    if (lane == 0) {
        asrc[node] = ps;
        adst[node] = pd;
    }
}

// ---------------------------------------------------------------------------
// Fused segment-softmax + weighted aggregation (+ bias, + optional BN+tanh).
// One 64-lane wave per destination node; lanes own VEC consecutive features.
// ---------------------------------------------------------------------------
template <int F, int VEC, bool ACT>
__global__ __launch_bounds__(256) void gat_agg(const float* __restrict__ h,
                                               const float* __restrict__ asrc,
                                               const float* __restrict__ adst,
                                               const int* __restrict__ row_ptr,
                                               const int* __restrict__ src_sorted,
                                               const float* __restrict__ bias,
                                               const float* __restrict__ gamma,
                                               const float* __restrict__ beta,
                                               const float* __restrict__ rmean,
                                               const float* __restrict__ rvar,
                                               float* __restrict__ out) {
    int wave = threadIdx.x >> 6;
    int lane = threadIdx.x & 63;
    int node = blockIdx.x * 4 + wave;
    if (node >= N_NODES) return;

    int start = row_ptr[node];
    int end = row_ptr[node + 1];
    float ad = adst[node];

    // pass 1: segment max of leaky_relu logits
    float m = -1e30f;
    for (int e = start + lane; e < end; e += 64) {
        int s = src_sorted[e];
        float l = asrc[s] + ad;
        l = (l > 0.f) ? l : NEG_SLOPE * l;
        m = fmaxf(m, l);
    }
#pragma unroll
    for (int off = 32; off; off >>= 1) m = fmaxf(m, __shfl_xor(m, off));

    // pass 2: exp weights + weighted feature accumulation
    constexpr bool ALL = (64 * VEC == F);
    const int f0 = lane * VEC;
    float denom = 0.f;
    float acc[VEC];
#pragma unroll
    for (int v = 0; v < VEC; v++) acc[v] = 0.f;

    for (int cs = start; cs < end; cs += 64) {
        int e = cs + lane;
        float w = 0.f;
        int s = 0;
        if (e < end) {
            s = src_sorted[e];
            float l = asrc[s] + ad;
            l = (l > 0.f) ? l : NEG_SLOPE * l;
            w = __expf(l - m);
        }
        denom += w;
        int cnt = min(64, end - cs);
        for (int j = 0; j < cnt; j++) {
            float wj = __shfl(w, j);
            int sj = __shfl(s, j);
            if (ALL || f0 < F) {
                const float* hp = h + (size_t)sj * F + f0;
                if constexpr (VEC == 4) {
                    float4 v = *reinterpret_cast<const float4*>(hp);
                    acc[0] += wj * v.x;
                    acc[1] += wj * v.y;
                    acc[2] += wj * v.z;
                    acc[3] += wj * v.w;
                } else if constexpr (VEC == 2) {
                    float2 v = *reinterpret_cast<const float2*>(hp);
                    acc[0] += wj * v.x;
                    acc[1] += wj * v.y;
                } else {
                    acc[0] += wj * hp[0];
                }
            }
        }
    }
#pragma unroll
    for (int off = 32; off; off >>= 1) denom += __shfl_xor(denom, off);
    float inv = 1.0f / denom;

    if (ALL || f0 < F) {
#pragma unroll
        for (int v = 0; v < VEC; v++) {
            int f = f0 + v;
            float val = acc[v] * inv + bias[f];
            if constexpr (ACT) {
                float rs = rsqrtf(rvar[f] + BN_EPS);
                val = tanhf((val - rmean[f]) * rs * gamma[f] + beta[f]);
            }
            out[(size_t)node * F + f] = val;
        }
    }
}

// ---------------------------------------------------------------------------

static inline size_t align256(size_t x) { return (x + 255) & ~(size_t)255; }

extern "C" void kernel_launch(void* const* d_in, const int* in_sizes, int n_in,
                              void* d_out, int out_size, void* d_ws, size_t ws_size,
                              hipStream_t stream) {
    const float* x  = (const float*)d_in[0];
    const int* ei   = (const int*)d_in[1];
    const float* w1 = (const float*)d_in[2];
    const float* as1 = (const float*)d_in[3];
    const float* ad1 = (const float*)d_in[4];
    const float* b1  = (const float*)d_in[5];
    const float* g1  = (const float*)d_in[6];
    const float* be1 = (const float*)d_in[7];
    const float* rm1 = (const float*)d_in[8];
    const float* rv1 = (const float*)d_in[9];
    const float* w2  = (const float*)d_in[10];
    const float* as2 = (const float*)d_in[11];
    const float* ad2 = (const float*)d_in[12];
    const float* b2  = (const float*)d_in[13];
    const float* g2  = (const float*)d_in[14];
    const float* be2 = (const float*)d_in[15];
    const float* rm2 = (const float*)d_in[16];
    const float* rv2 = (const float*)d_in[17];
    const float* w3  = (const float*)d_in[18];
    const float* as3 = (const float*)d_in[19];
    const float* ad3 = (const float*)d_in[20];
    const float* b3  = (const float*)d_in[21];
    float* out = (float*)d_out;

    char* p = (char*)d_ws;
    float* h_buf = (float*)p;  p += align256((size_t)N_NODES * 256 * 4);
    float* o_buf = (float*)p;  p += align256((size_t)N_NODES * 256 * 4);
    float* asrc  = (float*)p;  p += align256((size_t)N_NODES * 4);
    float* adst  = (float*)p;  p += align256((size_t)N_NODES * 4);
    int* counts    = (int*)p;  p += align256((size_t)N_NODES * 4);
    int* row_ptr   = (int*)p;  p += align256((size_t)(N_NODES + 1) * 4);
    int* write_pos = (int*)p;  p += align256((size_t)N_NODES * 4);
    int* src_sorted = (int*)p; p += align256((size_t)TOT_EDGES * 4);
    int* partials  = (int*)p;  p += align256(512 * 4);

    const int NB = (N_NODES + 255) / 256;  // 391 chunks

    // --- CSR build (graph identical for all layers) ---
    hipMemsetAsync(counts, 0, (size_t)N_NODES * 4, stream);
    count_kernel<<<4096, 256, 0, stream>>>(ei, counts);
    scan_partial<<<NB, 256, 0, stream>>>(counts, partials);
    scan_partials_kernel<<<1, 512, 0, stream>>>(partials, NB);
    scan_final<<<NB, 256, 0, stream>>>(counts, partials, row_ptr, write_pos);
    scatter_kernel<<<4096, 256, 0, stream>>>(ei, write_pos, src_sorted);

    const int NWB = (N_NODES + 3) / 4;  // wave-per-node grids (4 waves/block)
    const int MB = (N_NODES + TM - 1) / TM;

    // --- Layer 1: [N,128] @ [128,128] ---
    gemm_kernel<<<dim3(2, MB), 256, 0, stream>>>(x, w1, h_buf, N_NODES, 128, 128);
    row_dots<128><<<NWB, 256, 0, stream>>>(h_buf, as1, ad1, asrc, adst);
    gat_agg<128, 2, true><<<NWB, 256, 0, stream>>>(h_buf, asrc, adst, row_ptr,
                                                   src_sorted, b1, g1, be1, rm1, rv1, o_buf);

    // --- Layer 2: [N,128] @ [128,256] ---
    gemm_kernel<<<dim3(4, MB), 256, 0, stream>>>(o_buf, w2, h_buf, N_NODES, 128, 256);
    row_dots<256><<<NWB, 256, 0, stream>>>(h_buf, as2, ad2, asrc, adst);
    gat_agg<256, 4, true><<<NWB, 256, 0, stream>>>(h_buf, asrc, adst, row_ptr,
                                                   src_sorted, b2, g2, be2, rm2, rv2, o_buf);

    // --- Layer 3: [N,256] @ [256,40] ---
    gemm_kernel<<<dim3(1, MB), 256, 0, stream>>>(o_buf, w3, h_buf, N_NODES, 256, 40);
    row_dots<40><<<NWB, 256, 0, stream>>>(h_buf, as3, ad3, asrc, adst);
    gat_agg<40, 1, false><<<NWB, 256, 0, stream>>>(h_buf, asrc, adst, row_ptr,
                                                   src_sorted, b3, b3, b3, b3, b3, out);
}

// Round 2
// 1022.929 us; speedup vs baseline: 1.0869x; 1.0869x over previous
//
#include <hip/hip_runtime.h>
#include <hip/hip_bf16.h>
#include <cstddef>

#define N_NODES 100000
#define E_EDGES 1600000
#define TOT_EDGES (E_EDGES + N_NODES)
#define NEG_SLOPE 0.2f
#define BN_EPS 1e-5f

typedef __attribute__((ext_vector_type(8))) short short8;
typedef __attribute__((ext_vector_type(4))) float f32x4;

__device__ __forceinline__ unsigned short f2bf(float f) {
    union { float f; unsigned u; } c; c.f = f;
    unsigned u = c.u;
    u += 0x7fffu + ((u >> 16) & 1u);   // round-to-nearest-even
    return (unsigned short)(u >> 16);
}
__device__ __forceinline__ float bf2f(unsigned short h) {
    union { unsigned u; float f; } c; c.u = ((unsigned)h) << 16;
    return c.f;
}
__device__ __forceinline__ float bflo(unsigned u) {
    union { unsigned u; float f; } c; c.u = u << 16; return c.f;
}
__device__ __forceinline__ float bfhi(unsigned u) {
    union { unsigned u; float f; } c; c.u = u & 0xffff0000u; return c.f;
}

// ---------------------------------------------------------------------------
// CSR build: histogram of dst, exclusive scan, scatter src ids by dst.
// ---------------------------------------------------------------------------

__global__ __launch_bounds__(256) void count_kernel(const int* __restrict__ ei,
                                                    int* __restrict__ counts) {
    int idx = blockIdx.x * blockDim.x + threadIdx.x;
    int stride = gridDim.x * blockDim.x;
    for (int e = idx; e < TOT_EDGES; e += stride) {
        int d = (e < E_EDGES) ? ei[E_EDGES + e] : (e - E_EDGES);
        atomicAdd(&counts[d], 1);
    }
}

__global__ __launch_bounds__(256) void scan_partial(const int* __restrict__ counts,
                                                    int* __restrict__ partials) {
    __shared__ int s[256];
    int t = threadIdx.x;
    int i = blockIdx.x * 256 + t;
    s[t] = (i < N_NODES) ? counts[i] : 0;
    __syncthreads();
    for (int off = 128; off; off >>= 1) {
        if (t < off) s[t] += s[t + off];
        __syncthreads();
    }
    if (t == 0) partials[blockIdx.x] = s[0];
}

__global__ __launch_bounds__(512) void scan_partials_kernel(int* __restrict__ partials, int nb) {
    __shared__ int s[512];
    int t = threadIdx.x;
    int v = (t < nb) ? partials[t] : 0;
    s[t] = v;
    __syncthreads();
    for (int off = 1; off < 512; off <<= 1) {
        int y = (t >= off) ? s[t - off] : 0;
        __syncthreads();
        s[t] += y;
        __syncthreads();
    }
    if (t < nb) partials[t] = s[t] - v;  // exclusive
}

__global__ __launch_bounds__(256) void scan_final(const int* __restrict__ counts,
                                                  const int* __restrict__ partials,
                                                  int* __restrict__ row_ptr,
                                                  int* __restrict__ write_pos) {
    __shared__ int s[256];
    int t = threadIdx.x;
    int i = blockIdx.x * 256 + t;
    int v = (i < N_NODES) ? counts[i] : 0;
    s[t] = v;
    __syncthreads();
    for (int off = 1; off < 256; off <<= 1) {
        int y = (t >= off) ? s[t - off] : 0;
        __syncthreads();
        s[t] += y;
        __syncthreads();
    }
    int excl = s[t] - v;
    int rp = partials[blockIdx.x] + excl;
    if (i <= N_NODES) row_ptr[i] = rp;
    if (i < N_NODES) write_pos[i] = rp;
}

__global__ __launch_bounds__(256) void scatter_kernel(const int* __restrict__ ei,
                                                      int* __restrict__ write_pos,
                                                      int* __restrict__ src_sorted) {
    int idx = blockIdx.x * blockDim.x + threadIdx.x;
    int stride = gridDim.x * blockDim.x;
    for (int e = idx; e < TOT_EDGES; e += stride) {
        int srcv, d;
        if (e < E_EDGES) { srcv = ei[e]; d = ei[E_EDGES + e]; }
        else             { srcv = e - E_EDGES; d = srcv; }
        int p = atomicAdd(&write_pos[d], 1);
        src_sorted[p] = srcv;
    }
}

// ---------------------------------------------------------------------------
// Conversions: fp32 -> (hi, lo) bf16 planes.
// ---------------------------------------------------------------------------

__global__ __launch_bounds__(256) void xconv(const float* __restrict__ x,
                                             unsigned short* __restrict__ hi,
                                             unsigned short* __restrict__ lo, int n) {
    int idx = blockIdx.x * blockDim.x + threadIdx.x;
    int stride = gridDim.x * blockDim.x;
    for (int i = idx; i < n; i += stride) {
        float v = x[i];
        unsigned short h = f2bf(v);
        hi[i] = h;
        lo[i] = f2bf(v - bf2f(h));
    }
}

// W [K][Nn] fp32 -> BT [Np][K] bf16 hi/lo (rows n >= Nn zero-padded)
__global__ __launch_bounds__(256) void wconv(const float* __restrict__ W,
                                             unsigned short* __restrict__ bth,
                                             unsigned short* __restrict__ btl,
                                             int K, int Nn, int Np) {
    int idx = blockIdx.x * blockDim.x + threadIdx.x;
    int total = Np * K;
    if (idx >= total) return;
    int n = idx / K, k = idx % K;
    float v = (n < Nn) ? W[k * Nn + n] : 0.f;
    unsigned short h = f2bf(v);
    bth[idx] = h;
    btl[idx] = f2bf(v - bf2f(h));
}

// ---------------------------------------------------------------------------
// Split-bf16 MFMA GEMM: C[M,NACT] = (Ahi+Alo)[M,K] @ (Bhi+Blo)[K,N]
// B pre-transposed to [Npad][K].  Products: hi*hi + hi*lo + lo*hi.
// Wave computes 64 x (NTILES*16); block = 4 waves (MWAVES x NWAVES layout).
// Fragment layouts (measured, learn_hip m89/m91/m120):
//   A: A[m=lane&15][k=quad*8+j]   B: B[k=quad*8+j][n=lane&15]
//   D: row = quad*4+reg, col = lane&15
// ---------------------------------------------------------------------------
template<int K, int NTILES, int MWAVES, int NWAVES, int NACT, bool CFP32>
__global__ __launch_bounds__(256) void mfma_gemm(
    const unsigned short* __restrict__ Ahi, const unsigned short* __restrict__ Alo,
    const unsigned short* __restrict__ BThi, const unsigned short* __restrict__ BTlo,
    unsigned short* __restrict__ Chi, unsigned short* __restrict__ Clo,
    float* __restrict__ Cf, int M)
{
    int lane = threadIdx.x & 63;
    int wave = threadIdx.x >> 6;
    int quad = lane >> 4;
    int l16  = lane & 15;
    long mbase = (long)blockIdx.x * (64 * MWAVES) + (long)(wave / NWAVES) * 64;
    int n0 = (wave % NWAVES) * (NTILES * 16);

    const unsigned short* ah[4]; const unsigned short* al[4];
#pragma unroll
    for (int i = 0; i < 4; i++) {
        long r = mbase + i * 16 + l16;
        if (r > M - 1) r = M - 1;
        ah[i] = Ahi + r * K; al[i] = Alo + r * K;
    }
    const unsigned short* bh[NTILES]; const unsigned short* bl[NTILES];
#pragma unroll
    for (int j = 0; j < NTILES; j++) {
        long n = n0 + j * 16 + l16;
        bh[j] = BThi + n * K; bl[j] = BTlo + n * K;
    }
    const int ko = quad * 8;

    f32x4 acc[4][NTILES];
#pragma unroll
    for (int i = 0; i < 4; i++)
#pragma unroll
        for (int j = 0; j < NTILES; j++)
            acc[i][j] = (f32x4){0.f, 0.f, 0.f, 0.f};

    for (int k0 = 0; k0 < K; k0 += 32) {
        short8 vah[4], vall[4], vbh[NTILES], vbl[NTILES];
#pragma unroll
        for (int i = 0; i < 4; i++) {
            vah[i]  = *(const short8*)(ah[i] + k0 + ko);
            vall[i] = *(const short8*)(al[i] + k0 + ko);
        }
#pragma unroll
        for (int j = 0; j < NTILES; j++) {
            vbh[j] = *(const short8*)(bh[j] + k0 + ko);
            vbl[j] = *(const short8*)(bl[j] + k0 + ko);
        }
#pragma unroll
        for (int i = 0; i < 4; i++)
#pragma unroll
            for (int j = 0; j < NTILES; j++) {
                acc[i][j] = __builtin_amdgcn_mfma_f32_16x16x32_bf16(vah[i],  vbh[j], acc[i][j], 0, 0, 0);
                acc[i][j] = __builtin_amdgcn_mfma_f32_16x16x32_bf16(vah[i],  vbl[j], acc[i][j], 0, 0, 0);
                acc[i][j] = __builtin_amdgcn_mfma_f32_16x16x32_bf16(vall[i], vbh[j], acc[i][j], 0, 0, 0);
            }
    }

#pragma unroll
    for (int i = 0; i < 4; i++)
#pragma unroll
        for (int j = 0; j < NTILES; j++)
#pragma unroll
            for (int r = 0; r < 4; r++) {
                long row = mbase + i * 16 + quad * 4 + r;
                int col = n0 + j * 16 + l16;
                if (row < M && col < NACT) {
                    float v = acc[i][j][r];
                    if constexpr (CFP32) {
                        Cf[row * NACT + col] = v;
                    } else {
                        unsigned short h = f2bf(v);
                        Chi[row * NACT + col] = h;
                        Clo[row * NACT + col] = f2bf(v - bf2f(h));
                    }
                }
            }
}

// ---------------------------------------------------------------------------
// alpha_src/alpha_dst dot products (wave per node). h from hi+lo planes
// (near-fp32) or fp32 buffer.
// ---------------------------------------------------------------------------
template<int F, bool FIN32>
__global__ __launch_bounds__(256) void row_dots(
    const unsigned short* __restrict__ hhi, const unsigned short* __restrict__ hlo,
    const float* __restrict__ hf,
    const float* __restrict__ a_s, const float* __restrict__ a_d,
    float* __restrict__ asrc, float* __restrict__ adst)
{
    int wave = threadIdx.x >> 6;
    int lane = threadIdx.x & 63;
    int node = blockIdx.x * 4 + wave;
    if (node >= N_NODES) return;
    float ps = 0.f, pd = 0.f;
    for (int f = lane; f < F; f += 64) {
        size_t idx = (size_t)node * F + f;
        float v;
        if constexpr (FIN32) v = hf[idx];
        else                 v = bf2f(hhi[idx]) + bf2f(hlo[idx]);
        ps += v * a_s[f];
        pd += v * a_d[f];
    }
#pragma unroll
    for (int off = 32; off; off >>= 1) {
        ps += __shfl_xor(ps, off);
        pd += __shfl_xor(pd, off);
    }
    if (lane == 0) {
        asrc[node] = ps;
        adst[node] = pd;
    }
}

// ---------------------------------------------------------------------------
// Fused segment-softmax + weighted aggregation (+ bias, + optional BN+tanh).
// One wave per dst node. Gather from bf16-hi plane (G32=false) or fp32.
// Output: split hi/lo bf16 planes (OSPLIT) or fp32.
// ---------------------------------------------------------------------------
template<int F, int VEC, bool ACT, bool G32, bool OSPLIT>
__global__ __launch_bounds__(256) void gat_agg(
    const unsigned short* __restrict__ hbf, const float* __restrict__ hf,
    const float* __restrict__ asrc, const float* __restrict__ adst,
    const int* __restrict__ row_ptr, const int* __restrict__ src_sorted,
    const float* __restrict__ bias, const float* __restrict__ gamma,
    const float* __restrict__ beta, const float* __restrict__ rmean,
    const float* __restrict__ rvar,
    unsigned short* __restrict__ ohi, unsigned short* __restrict__ olo,
    float* __restrict__ outf)
{
    int wave = threadIdx.x >> 6;
    int lane = threadIdx.x & 63;
    int node = blockIdx.x * 4 + wave;
    if (node >= N_NODES) return;

    int start = row_ptr[node];
    int end = row_ptr[node + 1];
    float ad = adst[node];

    // pass 1: segment max of leaky_relu logits
    float m = -1e30f;
    for (int e = start + lane; e < end; e += 64) {
        int s = src_sorted[e];
        float l = asrc[s] + ad;
        l = (l > 0.f) ? l : NEG_SLOPE * l;
        m = fmaxf(m, l);
    }
#pragma unroll
    for (int off = 32; off; off >>= 1) m = fmaxf(m, __shfl_xor(m, off));

    constexpr bool ALL = (64 * VEC == F);
    const int f0 = lane * VEC;
    float denom = 0.f;
    float acc[VEC];
#pragma unroll
    for (int v = 0; v < VEC; v++) acc[v] = 0.f;

    for (int cs = start; cs < end; cs += 64) {
        int e = cs + lane;
        float w = 0.f;
        int s = 0;
        if (e < end) {
            s = src_sorted[e];
            float l = asrc[s] + ad;
            l = (l > 0.f) ? l : NEG_SLOPE * l;
            w = __expf(l - m);
        }
        denom += w;
        int cnt = min(64, end - cs);
        for (int j = 0; j < cnt; j++) {
            float wj = __shfl(w, j);
            int sj = __shfl(s, j);
            if (ALL || f0 < F) {
                if constexpr (G32) {
                    acc[0] += wj * hf[(size_t)sj * F + f0];
                } else if constexpr (VEC == 4) {
                    uint2 u = *reinterpret_cast<const uint2*>(hbf + (size_t)sj * F + f0);
                    acc[0] += wj * bflo(u.x);
                    acc[1] += wj * bfhi(u.x);
                    acc[2] += wj * bflo(u.y);
                    acc[3] += wj * bfhi(u.y);
                } else {  // VEC == 2
                    unsigned u = *reinterpret_cast<const unsigned*>(hbf + (size_t)sj * F + f0);
                    acc[0] += wj * bflo(u);
                    acc[1] += wj * bfhi(u);
                }
            }
        }
    }
#pragma unroll
    for (int off = 32; off; off >>= 1) denom += __shfl_xor(denom, off);
    float inv = 1.0f / denom;

    if (ALL || f0 < F) {
#pragma unroll
        for (int v = 0; v < VEC; v++) {
            int f = f0 + v;
            float val = acc[v] * inv + bias[f];
            if constexpr (ACT) {
                float rs = rsqrtf(rvar[f] + BN_EPS);
                val = tanhf((val - rmean[f]) * rs * gamma[f] + beta[f]);
            }
            size_t idx = (size_t)node * F + f;
            if constexpr (OSPLIT) {
                unsigned short h = f2bf(val);
                ohi[idx] = h;
                olo[idx] = f2bf(val - bf2f(h));
            } else {
                outf[idx] = val;
            }
        }
    }
}

// ---------------------------------------------------------------------------

static inline size_t align256(size_t x) { return (x + 255) & ~(size_t)255; }

extern "C" void kernel_launch(void* const* d_in, const int* in_sizes, int n_in,
                              void* d_out, int out_size, void* d_ws, size_t ws_size,
                              hipStream_t stream) {
    const float* x   = (const float*)d_in[0];
    const int* ei    = (const int*)d_in[1];
    const float* w1  = (const float*)d_in[2];
    const float* as1 = (const float*)d_in[3];
    const float* ad1 = (const float*)d_in[4];
    const float* b1  = (const float*)d_in[5];
    const float* g1  = (const float*)d_in[6];
    const float* be1 = (const float*)d_in[7];
    const float* rm1 = (const float*)d_in[8];
    const float* rv1 = (const float*)d_in[9];
    const float* w2  = (const float*)d_in[10];
    const float* as2 = (const float*)d_in[11];
    const float* ad2 = (const float*)d_in[12];
    const float* b2  = (const float*)d_in[13];
    const float* g2  = (const float*)d_in[14];
    const float* be2 = (const float*)d_in[15];
    const float* rm2 = (const float*)d_in[16];
    const float* rv2 = (const float*)d_in[17];
    const float* w3  = (const float*)d_in[18];
    const float* as3 = (const float*)d_in[19];
    const float* ad3 = (const float*)d_in[20];
    const float* b3  = (const float*)d_in[21];
    float* out = (float*)d_out;

    const size_t P128 = align256((size_t)N_NODES * 128 * 2);  // 25.6 MB
    const size_t P256 = align256((size_t)N_NODES * 256 * 2);  // 51.2 MB

    char* p = (char*)d_ws;
    // Region A: xhi|xlo -> o1hi|o1lo -> o2hi
    char* regA = p; p += P256;
    // Region B: h1hi -> h2hi -> h3f
    char* regB = p; p += P256;
    // Region C: h1lo -> h2lo -> o2lo
    char* regC = p; p += P256;

    unsigned short* xhi  = (unsigned short*)regA;
    unsigned short* xlo  = (unsigned short*)(regA + P128);
    unsigned short* o1hi = xhi;
    unsigned short* o1lo = xlo;
    unsigned short* o2hi = (unsigned short*)regA;
    unsigned short* h1hi = (unsigned short*)regB;
    unsigned short* h2hi = (unsigned short*)regB;
    float*          h3f  = (float*)regB;
    unsigned short* h1lo = (unsigned short*)regC;
    unsigned short* h2lo = (unsigned short*)regC;
    unsigned short* o2lo = (unsigned short*)regC;

    float* asrc = (float*)p;  p += align256((size_t)N_NODES * 4);
    float* adst = (float*)p;  p += align256((size_t)N_NODES * 4);
    int* counts    = (int*)p; p += align256((size_t)N_NODES * 4);
    int* row_ptr   = (int*)p; p += align256((size_t)(N_NODES + 1) * 4);
    int* write_pos = (int*)p; p += align256((size_t)N_NODES * 4);
    int* src_sorted = (int*)p; p += align256((size_t)TOT_EDGES * 4);
    int* partials  = (int*)p;  p += align256(512 * 4);
    unsigned short* w1th = (unsigned short*)p; p += align256(128 * 128 * 2);
    unsigned short* w1tl = (unsigned short*)p; p += align256(128 * 128 * 2);
    unsigned short* w2th = (unsigned short*)p; p += align256(256 * 128 * 2);
    unsigned short* w2tl = (unsigned short*)p; p += align256(256 * 128 * 2);
    unsigned short* w3th = (unsigned short*)p; p += align256(48 * 256 * 2);
    unsigned short* w3tl = (unsigned short*)p; p += align256(48 * 256 * 2);

    const int NB = (N_NODES + 255) / 256;

    // --- conversions ---
    xconv<<<4096, 256, 0, stream>>>(x, xhi, xlo, N_NODES * 128);
    wconv<<<(128 * 128 + 255) / 256, 256, 0, stream>>>(w1, w1th, w1tl, 128, 128, 128);
    wconv<<<(256 * 128 + 255) / 256, 256, 0, stream>>>(w2, w2th, w2tl, 128, 256, 256);
    wconv<<<(48 * 256 + 255) / 256, 256, 0, stream>>>(w3, w3th, w3tl, 256, 40, 48);

    // --- CSR build ---
    hipMemsetAsync(counts, 0, (size_t)N_NODES * 4, stream);
    count_kernel<<<4096, 256, 0, stream>>>(ei, counts);
    scan_partial<<<NB, 256, 0, stream>>>(counts, partials);
    scan_partials_kernel<<<1, 512, 0, stream>>>(partials, NB);
    scan_final<<<NB, 256, 0, stream>>>(counts, partials, row_ptr, write_pos);
    scatter_kernel<<<4096, 256, 0, stream>>>(ei, write_pos, src_sorted);

    const int NWB = (N_NODES + 3) / 4;
    const int G64 = (N_NODES + 63) / 64;
    const int G256 = (N_NODES + 255) / 256;

    // --- Layer 1: h1 = x @ w1  [N,128] ---
    mfma_gemm<128, 2, 1, 4, 128, false><<<G64, 256, 0, stream>>>(
        xhi, xlo, w1th, w1tl, h1hi, h1lo, nullptr, N_NODES);
    row_dots<128, false><<<NWB, 256, 0, stream>>>(h1hi, h1lo, nullptr, as1, ad1, asrc, adst);
    gat_agg<128, 2, true, false, true><<<NWB, 256, 0, stream>>>(
        h1hi, nullptr, asrc, adst, row_ptr, src_sorted,
        b1, g1, be1, rm1, rv1, o1hi, o1lo, nullptr);

    // --- Layer 2: h2 = o1 @ w2  [N,256] ---
    mfma_gemm<128, 4, 1, 4, 256, false><<<G64, 256, 0, stream>>>(
        o1hi, o1lo, w2th, w2tl, h2hi, h2lo, nullptr, N_NODES);
    row_dots<256, false><<<NWB, 256, 0, stream>>>(h2hi, h2lo, nullptr, as2, ad2, asrc, adst);
    gat_agg<256, 4, true, false, true><<<NWB, 256, 0, stream>>>(
        h2hi, nullptr, asrc, adst, row_ptr, src_sorted,
        b2, g2, be2, rm2, rv2, o2hi, o2lo, nullptr);

    // --- Layer 3: h3 = o2 @ w3  [N,40] (fp32 out) ---
    mfma_gemm<256, 3, 4, 1, 40, true><<<G256, 256, 0, stream>>>(
        o2hi, o2lo, w3th, w3tl, nullptr, nullptr, h3f, N_NODES);
    row_dots<40, true><<<NWB, 256, 0, stream>>>(nullptr, nullptr, h3f, as3, ad3, asrc, adst);
    gat_agg<40, 1, false, true, false><<<NWB, 256, 0, stream>>>(
        nullptr, h3f, asrc, adst, row_ptr, src_sorted,
        b3, b3, b3, b3, b3, nullptr, nullptr, out);
}